// Round 8
// baseline (6538.706 us; speedup 1.0000x reference)
//
#include <hip/hip_runtime.h>
#include <hip/hip_bf16.h>

typedef __attribute__((ext_vector_type(4))) float fx4;
typedef __attribute__((ext_vector_type(8))) short bf8;   // 8 x bf16
typedef __attribute__((ext_vector_type(4))) short sx4;   // 4 x bf16
typedef __attribute__((ext_vector_type(4))) int ix4;

#define NBLK 96          // 3 layers x 32 blocks
#define HSZ (32 * 512)   // one h plane (batch x hidden) in shorts

__device__ __forceinline__ short f2bf(float f) {
  __hip_bfloat16 h = __float2bfloat16(f);
  return *reinterpret_cast<short*>(&h);
}
__device__ __forceinline__ float bf2f(short s) {
  union { unsigned u; float f; } c; c.u = ((unsigned)(unsigned short)s) << 16; return c.f;
}
__device__ __forceinline__ float rcpf(float x) { return __builtin_amdgcn_rcpf(x); }
__device__ __forceinline__ bf8 asbf8(ix4 v) { union { ix4 i; bf8 b; } u; u.i = v; return u.b; }

// coherent (LLC) 16B load, bypasses local L1/L2 — for cross-XCD h broadcast
#define LDH(dst, p, OFF) \
  asm volatile("global_load_dwordx4 %0, %1, off offset:" OFF " sc0 sc1" \
               : "=v"(dst) : "v"(p) : "memory")
// plain cached 16B load (static data: x)
#define LDP(dst, p, OFF) \
  asm volatile("global_load_dwordx4 %0, %1, off offset:" OFF \
               : "=v"(dst) : "v"(p) : "memory")
// coherent 2B store (h publish)
#define STSH(p, v) \
  asm volatile("global_store_short %0, %1, off sc0 sc1" :: "v"(p), "v"(v) : "memory")

// x (B=32,T=512,D=256) fp32 -> xt (T,B,256) bf16 hi+lo (rows = t*32+b)
__global__ __launch_bounds__(256) void conv_x_k(const float* __restrict__ x,
                                                short* __restrict__ xhi, short* __restrict__ xlo) {
  int i = blockIdx.x * 256 + threadIdx.x;
  fx4 v = *(const fx4*)(x + (size_t)i * 4);
  int k = (i * 4) & 255;
  int row = (i * 4) >> 8;                            // b*512 + t
  int b = row >> 9, t = row & 511;
  sx4 hi, lo;
#pragma unroll
  for (int e = 0; e < 4; ++e) {
    hi[e] = f2bf(v[e]);
    lo[e] = f2bf(v[e] - bf2f(hi[e]));
  }
  size_t o = ((size_t)(t * 32 + b)) * 256 + k;
  *(sx4*)(xhi + o) = hi;
  *(sx4*)(xlo + o) = lo;
}

// weight slice -> register B-fragments (bf16 hi+lo), KS k-slices of 32
template<int KS>
__device__ __forceinline__ void load_w(bf8 (&bwh)[3][4], bf8 (&bwl)[3][4],
    const float* Wf, int wstr, int j0, int lm, int lk, int kbase) {
#pragma unroll
  for (int g = 0; g < 3; ++g) {
    const int grow = g * 512 + j0 + lm;
#pragma unroll
    for (int ks = 0; ks < KS; ++ks) {
      const float* src = Wf + (size_t)grow * wstr + kbase + ks * 32 + lk * 8;
      fx4 f0 = *(const fx4*)(src);
      fx4 f1 = *(const fx4*)(src + 4);
      bf8 vh, vl;
#pragma unroll
      for (int e = 0; e < 4; ++e) {
        vh[e] = f2bf(f0[e]);     vl[e] = f2bf(f0[e] - bf2f(vh[e]));
        vh[4 + e] = f2bf(f1[e]); vl[4 + e] = f2bf(f1[e] - bf2f(vh[4 + e]));
      }
      bwh[g][ks] = vh; bwl[g][ks] = vl;
    }
  }
}

// h (hi+lo) LLC loads: two 16-batch M-tiles, KS=4 k-slices
__device__ __forceinline__ void load_h4(ix4 (&rh)[2][4], ix4 (&rl)[2][4],
    const short* base, int lm, int lk, int kbase) {
  const short* p0 = base + (size_t)lm * 512 + kbase + lk * 8;
  const short* p1 = p0 + 16 * 512;
  const short* q0 = p0 + HSZ;
  const short* q1 = p1 + HSZ;
  LDH(rh[0][0], p0, "0"); LDH(rh[0][1], p0, "64"); LDH(rh[0][2], p0, "128"); LDH(rh[0][3], p0, "192");
  LDH(rh[1][0], p1, "0"); LDH(rh[1][1], p1, "64"); LDH(rh[1][2], p1, "128"); LDH(rh[1][3], p1, "192");
  LDH(rl[0][0], q0, "0"); LDH(rl[0][1], q0, "64"); LDH(rl[0][2], q0, "128"); LDH(rl[0][3], q0, "192");
  LDH(rl[1][0], q1, "0"); LDH(rl[1][1], q1, "64"); LDH(rl[1][2], q1, "128"); LDH(rl[1][3], q1, "192");
}

template<int KS>
__device__ __forceinline__ void do_mfma(fx4 (&acc)[2][3],
    const ix4 (&rh)[2][4], const ix4 (&rl)[2][4],
    const bf8 (&bwh)[3][4], const bf8 (&bwl)[3][4]) {
#pragma unroll
  for (int ks = 0; ks < KS; ++ks) {
#pragma unroll
    for (int mt = 0; mt < 2; ++mt) {
      bf8 ah = asbf8(rh[mt][ks]);
      bf8 al = asbf8(rl[mt][ks]);
#pragma unroll
      for (int g = 0; g < 3; ++g) {
        acc[mt][g] = __builtin_amdgcn_mfma_f32_16x16x32_bf16(ah, bwh[g][ks], acc[mt][g], 0, 0, 0);
        acc[mt][g] = __builtin_amdgcn_mfma_f32_16x16x32_bf16(al, bwh[g][ks], acc[mt][g], 0, 0, 0);
        acc[mt][g] = __builtin_amdgcn_mfma_f32_16x16x32_bf16(ah, bwl[g][ks], acc[mt][g], 0, 0, 0);
      }
    }
  }
}

// 3-layer pipelined persistent recurrence. 96 blocks x 512 thr (8 waves).
// Block (L = bid>>5, p = bid&31) owns 16 output cols j0 = p*16 of layer L.
// Waves 0-3: input GEMM (x for L0 [K=256, 64/wave], h_{L-1,s} else [128/wave]).
// Waves 4-7: h2h GEMM (h_{L,s-1}, 128/wave). Weights register-resident hi+lo.
//
// SYNC: one counter per layer (cnt[L*16]); each wave, after draining its
// coherent stores, does atomicAdd(+1). 32 blocks x 8 waves = 256 adds/step:
// cnt_L == 256*(s+2) <=> layer L fully completed step s (init counts as
// "step -1": cnt=256). Step-s preconditions (polled by wave 0, lanes 0-2):
//   prev cnt >= 256*(s+2) | own cnt >= 256*(s+1) | next cnt >= 256*(s-1)
// (next gates overwriting tri-buffer plane s%3 = h_{L,s-3}).
// hg per layer: [buf 3][hi/lo 2][32][512] bf16; step s -> buf s%3.
template<int L>
__device__ __forceinline__ void rec3_body(
    float (*m_lds)[32][52], float* bias_s,
    const short* __restrict__ xth, const short* __restrict__ xtl,
    const float* __restrict__ Wi, const float* __restrict__ bi,
    const float* __restrict__ Wh, const float* __restrict__ bh,
    short* __restrict__ hg, int* cnt, float* __restrict__ out)
{
  const int tid = threadIdx.x;
  const int bid = blockIdx.x;
  const int j0 = (bid & 31) * 16;
  const int w = tid >> 6, lane = tid & 63, lm = lane & 15, lk = lane >> 4;
  const bool inW = (w < 4);
  constexpr int KIN = (L == 0) ? 256 : 512;

  short* hgl = hg + (size_t)L * 6 * HSZ;
  const short* hgp = (L > 0) ? (hg + (size_t)(L - 1) * 6 * HSZ) : hg;

  const int kbase = inW ? w * (KIN / 4) : (w - 4) * 128;

  bf8 bwh[3][4], bwl[3][4];
  if (inW) {
    if constexpr (L == 0) load_w<2>(bwh, bwl, Wi, KIN, j0, lm, lk, kbase);
    else                  load_w<4>(bwh, bwl, Wi, KIN, j0, lm, lk, kbase);
  } else {
    load_w<4>(bwh, bwl, Wh, 512, j0, lm, lk, kbase);
  }
  if (tid < 48) bias_s[tid] = bi[(tid >> 4) * 512 + j0 + (tid & 15)];
  else if (tid >= 64 && tid < 112) {
    const int u = tid - 64;
    bias_s[48 + u] = bh[(u >> 4) * 512 + j0 + (u & 15)];
  }
  if (tid < 256) {  // zero own buf 2 (hi+lo): h_{L,-1}=0, read at s=0
    const int b = tid >> 3, zc = (tid & 7) * 2;
    __hip_atomic_store((int*)(hgl + (size_t)4 * HSZ + b * 512 + j0 + zc), 0,
                       __ATOMIC_RELAXED, __HIP_MEMORY_SCOPE_AGENT);
    __hip_atomic_store((int*)(hgl + (size_t)5 * HSZ + b * 512 + j0 + zc), 0,
                       __ATOMIC_RELAXED, __HIP_MEMORY_SCOPE_AGENT);
  }
  asm volatile("s_waitcnt vmcnt(0)" ::: "memory");  // per-wave drain of zeros
  if (lane == 0)
    __hip_atomic_fetch_add(cnt + L * 16, 1, __ATOMIC_RELAXED, __HIP_MEMORY_SCOPE_AGENT);

  const int cb = tid >> 4, cc = tid & 15;   // cell phase: (batch, 1 col)
  float hv = 0.f;
  int bufw = 0;                             // s % 3

  for (int s = 0; s < 512; ++s) {
    ix4 rh[2][4], rl[2][4];
    if (L == 0 && inW) {   // x static — prefetch before the wait
      const short* x0 = xth + (size_t)(s * 32 + lm) * 256 + kbase + lk * 8;
      const short* x1 = x0 + 16 * 256;
      const short* y0 = xtl + (size_t)(s * 32 + lm) * 256 + kbase + lk * 8;
      const short* y1 = y0 + 16 * 256;
      LDP(rh[0][0], x0, "0"); LDP(rh[0][1], x0, "64");
      LDP(rh[1][0], x1, "0"); LDP(rh[1][1], x1, "64");
      LDP(rl[0][0], y0, "0"); LDP(rl[0][1], y0, "64");
      LDP(rl[1][0], y1, "0"); LDP(rl[1][1], y1, "64");
    }

    if (w == 0) {   // 3 poller lanes, 3 LLC lines total
      const int* cp = nullptr; int need = 0;
      if (lane == 0)               { cp = cnt + L * 16;       need = 256 * (s + 1); }
      else if (lane == 1 && L > 0) { cp = cnt + (L - 1) * 16; need = 256 * (s + 2); }
      else if (lane == 2 && L < 2) { cp = cnt + (L + 1) * 16; need = 256 * (s - 1); }
      if (cp)
        while (__hip_atomic_load(cp, __ATOMIC_RELAXED, __HIP_MEMORY_SCOPE_AGENT) < need)
          __builtin_amdgcn_s_sleep(2);
    }
    __syncthreads();

    const int bufr = (bufw == 0) ? 2 : bufw - 1;   // (s-1) % 3
    if (inW) {
      if constexpr (L > 0)
        load_h4(rh, rl, hgp + (size_t)(bufw * 2) * HSZ, lm, lk, kbase);
    } else {
      load_h4(rh, rl, hgl + (size_t)(bufr * 2) * HSZ, lm, lk, kbase);
    }
    asm volatile("s_waitcnt vmcnt(0)" ::: "memory");
    __builtin_amdgcn_sched_barrier(0);   // rule #18

    fx4 acc[2][3];
#pragma unroll
    for (int mt = 0; mt < 2; ++mt)
#pragma unroll
      for (int g = 0; g < 3; ++g) acc[mt][g] = (fx4){0.f, 0.f, 0.f, 0.f};
    if (inW) {
      if constexpr (L == 0) do_mfma<2>(acc, rh, rl, bwh, bwl);
      else                  do_mfma<4>(acc, rh, rl, bwh, bwl);
    } else {
      do_mfma<4>(acc, rh, rl, bwh, bwl);
    }

#pragma unroll
    for (int mt = 0; mt < 2; ++mt)
#pragma unroll
      for (int g = 0; g < 3; ++g)
#pragma unroll
        for (int q = 0; q < 4; ++q)
          m_lds[w][mt * 16 + lk * 4 + q][g * 16 + lm] = acc[mt][g][q];
    __syncthreads();

    // cell: planes 0-3 input partials, 4-7 h2h partials; 1 col/thread
    float ain[3], hhv[3];
#pragma unroll
    for (int g = 0; g < 3; ++g) {
      const int col = g * 16 + cc;
      ain[g] = m_lds[0][cb][col] + m_lds[1][cb][col] + m_lds[2][cb][col] +
               m_lds[3][cb][col] + bias_s[col];
      hhv[g] = m_lds[4][cb][col] + m_lds[5][cb][col] + m_lds[6][cb][col] +
               m_lds[7][cb][col] + bias_s[48 + col];
    }
    float pr = ain[0] + hhv[0];
    float pz = ain[1] + hhv[1];
    float h2n = hhv[2];
    float pn = ain[2] + h2n;
    float sr = rcpf(1.f + __expf(-pr));  // sigmoid
    float rr = __expf(-__expf(-sr));     // Gumbel squash
    float sz = rcpf(1.f + __expf(-pz));
    float zz = __expf(-__expf(-sz));
    float na = pn + rr * h2n;
    float ex = __expf(2.f * na);         // tanh via exp
    float nn = 1.f - 2.f * rcpf(ex + 1.f);
    float hnew = (1.f - zz) * nn + zz * hv;
    hv = hnew;
    short hh_ = f2bf(hnew);
    short hl_ = f2bf(hnew - bf2f(hh_));
    short* hw = hgl + (size_t)(bufw * 2) * HSZ + (size_t)cb * 512 + j0 + cc;
    STSH(hw, hh_);
    STSH(hw + HSZ, hl_);
    if (L == 2 && s == 511) out[(size_t)cb * 512 + j0 + cc] = hnew;

    asm volatile("s_waitcnt vmcnt(0)" ::: "memory");  // per-wave drain (release)
    if (lane == 0)
      __hip_atomic_fetch_add(cnt + L * 16, 1, __ATOMIC_RELAXED, __HIP_MEMORY_SCOPE_AGENT);

    bufw = (bufw == 2) ? 0 : bufw + 1;
  }
}

__global__ __launch_bounds__(512, 1) void rec3(
    const short* __restrict__ xth, const short* __restrict__ xtl,
    const float* __restrict__ Wi0, const float* __restrict__ bi0,
    const float* __restrict__ Wh0, const float* __restrict__ bh0,
    const float* __restrict__ Wi1, const float* __restrict__ bi1,
    const float* __restrict__ Wh1, const float* __restrict__ bh1,
    const float* __restrict__ Wi2, const float* __restrict__ bi2,
    const float* __restrict__ Wh2, const float* __restrict__ bh2,
    short* __restrict__ hg, int* cnt, float* __restrict__ out)
{
  __shared__ __align__(16) float m_lds[8][32][52];
  __shared__ float bias_s[96];
  const int l = blockIdx.x >> 5;
  if (l == 0)
    rec3_body<0>(m_lds, bias_s, xth, xtl, Wi0, bi0, Wh0, bh0, hg, cnt, out);
  else if (l == 1)
    rec3_body<1>(m_lds, bias_s, nullptr, nullptr, Wi1, bi1, Wh1, bh1, hg, cnt, out);
  else
    rec3_body<2>(m_lds, bias_s, nullptr, nullptr, Wi2, bi2, Wh2, bh2, hg, cnt, out);
}

extern "C" void kernel_launch(void* const* d_in, const int* in_sizes, int n_in,
                              void* d_out, int out_size, void* d_ws, size_t ws_size,
                              hipStream_t stream) {
  const float* x   = (const float*)d_in[0];
  const float* Wi0 = (const float*)d_in[1];
  const float* bi0 = (const float*)d_in[2];
  const float* Wh0 = (const float*)d_in[3];
  const float* bh0 = (const float*)d_in[4];
  const float* Wi1 = (const float*)d_in[5];
  const float* bi1 = (const float*)d_in[6];
  const float* Wh1 = (const float*)d_in[7];
  const float* bh1 = (const float*)d_in[8];
  const float* Wi2 = (const float*)d_in[9];
  const float* bi2 = (const float*)d_in[10];
  const float* Wh2 = (const float*)d_in[11];
  const float* bh2 = (const float*)d_in[12];
  float* out = (float*)d_out;
  (void)in_sizes; (void)n_in; (void)out_size; (void)ws_size;

  char* ws = (char*)d_ws;
  size_t off = 0;
  auto alloc = [&](size_t b) { char* p = ws + off; off = (off + b + 255) & ~(size_t)255; return p; };
  short* xth   = (short*)alloc(16384ull * 256 * 2);   // 8.4 MB
  short* xtl   = (short*)alloc(16384ull * 256 * 2);
  short* hg    = (short*)alloc(3ull * 6 * HSZ * 2);   // 3 layers x [3buf][hi/lo][32][512]
  int*   cnt   = (int*)alloc(3 * 16 * 4);             // 3 layer counters, 64B apart

  hipMemsetAsync(cnt, 0, 3 * 16 * 4, stream);
  hipLaunchKernelGGL(conv_x_k, dim3(4096), dim3(256), 0, stream, x, xth, xtl);
  hipLaunchKernelGGL(rec3, dim3(NBLK), dim3(512), 0, stream,
                     xth, xtl,
                     Wi0, bi0, Wh0, bh0,
                     Wi1, bi1, Wh1, bh1,
                     Wi2, bi2, Wh2, bh2,
                     hg, cnt, out);
}

// Round 9
// 3518.998 us; speedup vs baseline: 1.8581x; 1.8581x over previous
//
#include <hip/hip_runtime.h>
#include <hip/hip_bf16.h>

typedef __attribute__((ext_vector_type(4))) float fx4;
typedef __attribute__((ext_vector_type(8))) short bf8;   // 8 x bf16
typedef __attribute__((ext_vector_type(4))) short sx4;   // 4 x bf16
typedef __attribute__((ext_vector_type(4))) int ix4;

#define NBLK 96          // 3 layers x 32 compute blocks
#define HSZ (32 * 512)   // one h plane (batch x hidden) in shorts

__device__ __forceinline__ short f2bf(float f) {
  __hip_bfloat16 h = __float2bfloat16(f);
  return *reinterpret_cast<short*>(&h);
}
__device__ __forceinline__ float bf2f(short s) {
  union { unsigned u; float f; } c; c.u = ((unsigned)(unsigned short)s) << 16; return c.f;
}
__device__ __forceinline__ float rcpf(float x) { return __builtin_amdgcn_rcpf(x); }
__device__ __forceinline__ bf8 asbf8(ix4 v) { union { ix4 i; bf8 b; } u; u.i = v; return u.b; }

// coherent (LLC) 16B load, bypasses local L1/L2 — for cross-XCD h broadcast
#define LDH(dst, p, OFF) \
  asm volatile("global_load_dwordx4 %0, %1, off offset:" OFF " sc0 sc1" \
               : "=v"(dst) : "v"(p) : "memory")
// plain cached 16B load (static data: x)
#define LDP(dst, p, OFF) \
  asm volatile("global_load_dwordx4 %0, %1, off offset:" OFF \
               : "=v"(dst) : "v"(p) : "memory")
#define LD8(OP, A, P) do { \
  OP(A[0], P, "0");   OP(A[1], P, "64");  OP(A[2], P, "128"); OP(A[3], P, "192"); \
  OP(A[4], P, "256"); OP(A[5], P, "320"); OP(A[6], P, "384"); OP(A[7], P, "448"); } while (0)

// x (B=32,T=512,D=256) fp32 -> xt (T,B,256) bf16 hi+lo (rows = t*32+b)
__global__ __launch_bounds__(256) void conv_x_k(const float* __restrict__ x,
                                                short* __restrict__ xhi, short* __restrict__ xlo) {
  int i = blockIdx.x * 256 + threadIdx.x;
  fx4 v = *(const fx4*)(x + (size_t)i * 4);
  int k = (i * 4) & 255;
  int row = (i * 4) >> 8;                            // b*512 + t
  int b = row >> 9, t = row & 511;
  sx4 hi, lo;
#pragma unroll
  for (int e = 0; e < 4; ++e) {
    hi[e] = f2bf(v[e]);
    lo[e] = f2bf(v[e] - bf2f(hi[e]));
  }
  size_t o = ((size_t)(t * 32 + b)) * 256 + k;
  *(sx4*)(xhi + o) = hi;
  *(sx4*)(xlo + o) = lo;
}

// Per-layer body, templated so every loop bound / stride is compile-time.
// Layer L, 32 blocks; block owns 16 output cols j0. Step s runs at tick t=s+L.
//
// FLAG PROTOCOL (flag[b] = completed step of block b, +3; init 2). Aggregator
// block per layer publishes agg[L] = min over its 32 blocks' flags. Step-s
// preconditions (polled on agg only, 3 lanes):
//   prev-layer  agg >= s+3  (prev completed s   -> h_{L-1,s}   readable)
//   own-layer   agg >= s+2  (peers completed s-1-> h_{L,s-1}   readable)
//   next-layer  agg >= s    (next completed s-3 -> tri-buffer plane s%3 free)
// hg per layer: [buf 3][hi/lo 2][32][512] bf16; step s -> buf s%3.
template<int L>
__device__ __forceinline__ void rec3_body(
    float (*m_lds)[32][52], float* bias_s,
    const short* __restrict__ xth, const short* __restrict__ xtl,
    const float* __restrict__ Wi, const float* __restrict__ bi,
    const float* __restrict__ Wh, const float* __restrict__ bh,
    short* __restrict__ hg, int* flags, int* agg, float* __restrict__ out)
{
  const int tid = threadIdx.x;
  const int bid = blockIdx.x;
  const int j0 = (bid & 31) * 16;
  const int w = tid >> 6, lane = tid & 63, lm = lane & 15, lk = lane >> 4;
  const bool inW = (w < 2);
  constexpr int KIN = (L == 0) ? 256 : 512;

  short* hgl = hg + (size_t)L * 6 * HSZ;
  const short* hgp = (L > 0) ? (hg + (size_t)(L - 1) * 6 * HSZ) : hg;

  // L==0 input waves: M-split (wave w covers batches w*16..w*16+15), full K=256.
  // All other waves: K-split (256 each), both 16-batch M-tiles.
  const int kbase = inW ? ((L == 0) ? 0 : w * 256) : (w - 2) * 256;
  const float* Wf = inW ? Wi : Wh;
  const int wstr = inW ? KIN : 512;

  // ---- weight slice -> register B-fragments, bf16 hi+lo (static 3x8) ----
  bf8 bwh[3][8], bwl[3][8];
#pragma unroll
  for (int g = 0; g < 3; ++g) {
    const int grow = g * 512 + j0 + lm;
#pragma unroll
    for (int ks = 0; ks < 8; ++ks) {
      const float* src = Wf + (size_t)grow * wstr + kbase + ks * 32 + lk * 8;
      fx4 f0 = *(const fx4*)(src);
      fx4 f1 = *(const fx4*)(src + 4);
      bf8 vh, vl;
#pragma unroll
      for (int e = 0; e < 4; ++e) {
        vh[e] = f2bf(f0[e]);     vl[e] = f2bf(f0[e] - bf2f(vh[e]));
        vh[4 + e] = f2bf(f1[e]); vl[4 + e] = f2bf(f1[e] - bf2f(vh[4 + e]));
      }
      bwh[g][ks] = vh; bwl[g][ks] = vl;
    }
  }
  if (tid < 48) bias_s[tid] = bi[(tid >> 4) * 512 + j0 + (tid & 15)];
  else if (tid < 96) {
    const int u = tid - 48;
    bias_s[48 + u] = bh[(u >> 4) * 512 + j0 + (u & 15)];
  }
  {  // zero own buf 2 (hi+lo): h_{L,-1} = 0, read at s=0 (bufr = (0-1)%3 = 2)
    const int b = tid >> 3, zc = (tid & 7) * 2;
    __hip_atomic_store((int*)(hgl + (size_t)4 * HSZ + b * 512 + j0 + zc), 0,
                       __ATOMIC_RELAXED, __HIP_MEMORY_SCOPE_AGENT);
    __hip_atomic_store((int*)(hgl + (size_t)5 * HSZ + b * 512 + j0 + zc), 0,
                       __ATOMIC_RELAXED, __HIP_MEMORY_SCOPE_AGENT);
  }
  __syncthreads();   // drain stores before flag (release)
  if (tid == 0)
    __hip_atomic_store(flags + bid * 32, 2, __ATOMIC_RELAXED, __HIP_MEMORY_SCOPE_AGENT);

  const int cb = tid >> 3, c2 = (tid & 7) * 2;   // cell phase: (batch, 2 cols)
  float hv0 = 0.f, hv1 = 0.f;
  int bufw = 0;                                   // s % 3

  for (int s = 0; s < 512; ++s) {
    ix4 rh[2][8], rl[2][8];
    if (L == 0 && inW) {   // x is static — prefetch before the wait
      const short* xh = xth + (size_t)(s * 32 + w * 16 + lm) * 256 + lk * 8;
      const short* xl = xtl + (size_t)(s * 32 + w * 16 + lm) * 256 + lk * 8;
      LD8(LDP, rh[0], xh);
      LD8(LDP, rl[0], xl);
    }

    // poll ONLY the per-layer aggregate lines (3 lanes, 3 cache lines)
    {
      const int* cp = nullptr; int need = 0;
      if (tid == 0)               { cp = agg + L * 16;       need = s + 2; }
      else if (tid == 1 && L > 0) { cp = agg + (L - 1) * 16; need = s + 3; }
      else if (tid == 2 && L < 2) { cp = agg + (L + 1) * 16; need = s; }
      if (cp)
        while (__hip_atomic_load(cp, __ATOMIC_RELAXED, __HIP_MEMORY_SCOPE_AGENT) < need)
          __builtin_amdgcn_s_sleep(1);
    }
    __syncthreads();

    const int bufr = (bufw == 0) ? 2 : bufw - 1;   // (s-1) % 3
    if (!(L == 0 && inW)) {
      const short* basep = inW ? (hgp + (size_t)(bufw * 2) * HSZ)
                               : (hgl + (size_t)(bufr * 2) * HSZ);
      const short* s0h = basep + (size_t)lm * 512 + kbase + lk * 8;
      const short* s1h = s0h + 16 * 512;
      const short* s0l = s0h + HSZ;
      const short* s1l = s1h + HSZ;
      LD8(LDH, rh[0], s0h); LD8(LDH, rh[1], s1h);
      LD8(LDH, rl[0], s0l); LD8(LDH, rl[1], s1l);
    }
    asm volatile("s_waitcnt vmcnt(0)" ::: "memory");
    __builtin_amdgcn_sched_barrier(0);   // rule #18

    fx4 acc[2][3];
#pragma unroll
    for (int mt = 0; mt < 2; ++mt)
#pragma unroll
      for (int g = 0; g < 3; ++g) acc[mt][g] = (fx4){0.f, 0.f, 0.f, 0.f};

    if (L == 0 && inW) {
#pragma unroll
      for (int ks = 0; ks < 8; ++ks) {
        bf8 ah = asbf8(rh[0][ks]);
        bf8 al = asbf8(rl[0][ks]);
#pragma unroll
        for (int g = 0; g < 3; ++g) {
          acc[0][g] = __builtin_amdgcn_mfma_f32_16x16x32_bf16(ah, bwh[g][ks], acc[0][g], 0, 0, 0);
          acc[0][g] = __builtin_amdgcn_mfma_f32_16x16x32_bf16(al, bwh[g][ks], acc[0][g], 0, 0, 0);
          acc[0][g] = __builtin_amdgcn_mfma_f32_16x16x32_bf16(ah, bwl[g][ks], acc[0][g], 0, 0, 0);
        }
      }
    } else {
#pragma unroll
      for (int ks = 0; ks < 8; ++ks) {
#pragma unroll
        for (int mt = 0; mt < 2; ++mt) {
          bf8 ah = asbf8(rh[mt][ks]);
          bf8 al = asbf8(rl[mt][ks]);
#pragma unroll
          for (int g = 0; g < 3; ++g) {
            acc[mt][g] = __builtin_amdgcn_mfma_f32_16x16x32_bf16(ah, bwh[g][ks], acc[mt][g], 0, 0, 0);
            acc[mt][g] = __builtin_amdgcn_mfma_f32_16x16x32_bf16(al, bwh[g][ks], acc[mt][g], 0, 0, 0);
            acc[mt][g] = __builtin_amdgcn_mfma_f32_16x16x32_bf16(ah, bwl[g][ks], acc[mt][g], 0, 0, 0);
          }
        }
      }
    }

    if (L == 0 && inW) {   // wave w -> rows w*16.. of partial plane 0
#pragma unroll
      for (int g = 0; g < 3; ++g)
#pragma unroll
        for (int q = 0; q < 4; ++q)
          m_lds[0][w * 16 + lk * 4 + q][g * 16 + lm] = acc[0][g][q];
    } else {
#pragma unroll
      for (int mt = 0; mt < 2; ++mt)
#pragma unroll
        for (int g = 0; g < 3; ++g)
#pragma unroll
          for (int q = 0; q < 4; ++q)
            m_lds[w][mt * 16 + lk * 4 + q][g * 16 + lm] = acc[mt][g][q];
    }
    __syncthreads();

    // cell: planes 0(,1) = input partial(s), 2,3 = h2h K-halves
    float av[3][2], hh[3][2];
#pragma unroll
    for (int g = 0; g < 3; ++g)
#pragma unroll
      for (int e = 0; e < 2; ++e) {
        const int c = g * 16 + c2 + e;
        float ain = m_lds[0][cb][c];
        if (L > 0) ain += m_lds[1][cb][c];
        av[g][e] = ain + bias_s[c];
        hh[g][e] = m_lds[2][cb][c] + m_lds[3][cb][c] + bias_s[48 + c];
      }
    float hvv[2] = {hv0, hv1}, hn[2];
#pragma unroll
    for (int e = 0; e < 2; ++e) {
      float pr = av[0][e] + hh[0][e];
      float pz = av[1][e] + hh[1][e];
      float h2n = hh[2][e];
      float pn = av[2][e] + h2n;
      float sr = rcpf(1.f + __expf(-pr));  // sigmoid
      float rr = __expf(-__expf(-sr));     // Gumbel squash
      float sz = rcpf(1.f + __expf(-pz));
      float zz = __expf(-__expf(-sz));
      float na = pn + rr * h2n;
      float ex = __expf(2.f * na);         // tanh via exp
      float nn = 1.f - 2.f * rcpf(ex + 1.f);
      hn[e] = (1.f - zz) * nn + zz * hvv[e];
    }
    hv0 = hn[0]; hv1 = hn[1];
    short h0h = f2bf(hn[0]), h0l = f2bf(hn[0] - bf2f(h0h));
    short h1h = f2bf(hn[1]), h1l = f2bf(hn[1] - bf2f(h1h));
    int packh = (int)(unsigned short)h0h | ((int)(unsigned short)h1h << 16);
    int packl = (int)(unsigned short)h0l | ((int)(unsigned short)h1l << 16);

    short* hw = hgl + (size_t)(bufw * 2) * HSZ;
    __hip_atomic_store((int*)(hw + (size_t)cb * 512 + j0 + c2), packh,
                       __ATOMIC_RELAXED, __HIP_MEMORY_SCOPE_AGENT);
    __hip_atomic_store((int*)(hw + HSZ + (size_t)cb * 512 + j0 + c2), packl,
                       __ATOMIC_RELAXED, __HIP_MEMORY_SCOPE_AGENT);
    if (L == 2 && s == 511) {
      out[(size_t)cb * 512 + j0 + c2] = hn[0];
      out[(size_t)cb * 512 + j0 + c2 + 1] = hn[1];
    }
    __syncthreads();   // vmcnt(0) drain in every wave before the flag = release
    if (tid == 0)
      __hip_atomic_store(flags + bid * 32, s + 3,
                         __ATOMIC_RELAXED, __HIP_MEMORY_SCOPE_AGENT);

    bufw = (bufw == 2) ? 0 : bufw + 1;
  }
}

__global__ __launch_bounds__(256, 1) void rec3(
    const short* __restrict__ xth, const short* __restrict__ xtl,
    const float* __restrict__ Wi0, const float* __restrict__ bi0,
    const float* __restrict__ Wh0, const float* __restrict__ bh0,
    const float* __restrict__ Wi1, const float* __restrict__ bi1,
    const float* __restrict__ Wh1, const float* __restrict__ bh1,
    const float* __restrict__ Wi2, const float* __restrict__ bi2,
    const float* __restrict__ Wh2, const float* __restrict__ bh2,
    short* __restrict__ hg, int* flags, int* agg, float* __restrict__ out)
{
  const int bid = blockIdx.x;
  if (bid >= NBLK) {
    // ---- aggregator block for layer FL: poll 32 flags, publish agg[FL] ----
    const int FL = bid - NBLK;
    if (threadIdx.x >= 64) return;          // single wave
    const int lane = threadIdx.x;
    const int* fp = flags + (FL * 32 + (lane & 31)) * 32;
    int* ap = agg + FL * 16;
    for (int s = -1; s < 512; ++s) {
      const int target = s + 3;
      while (true) {
        int v = __hip_atomic_load(fp, __ATOMIC_RELAXED, __HIP_MEMORY_SCOPE_AGENT);
        if (__all(v >= target)) break;
        __builtin_amdgcn_s_sleep(1);
      }
      if (lane == 0)
        __hip_atomic_store(ap, target, __ATOMIC_RELAXED, __HIP_MEMORY_SCOPE_AGENT);
    }
    return;
  }
  __shared__ __align__(16) float m_lds[4][32][52];
  __shared__ float bias_s[96];
  const int l = bid >> 5;
  if (l == 0)
    rec3_body<0>(m_lds, bias_s, xth, xtl, Wi0, bi0, Wh0, bh0, hg, flags, agg, out);
  else if (l == 1)
    rec3_body<1>(m_lds, bias_s, nullptr, nullptr, Wi1, bi1, Wh1, bh1, hg, flags, agg, out);
  else
    rec3_body<2>(m_lds, bias_s, nullptr, nullptr, Wi2, bi2, Wh2, bh2, hg, flags, agg, out);
}

extern "C" void kernel_launch(void* const* d_in, const int* in_sizes, int n_in,
                              void* d_out, int out_size, void* d_ws, size_t ws_size,
                              hipStream_t stream) {
  const float* x   = (const float*)d_in[0];
  const float* Wi0 = (const float*)d_in[1];
  const float* bi0 = (const float*)d_in[2];
  const float* Wh0 = (const float*)d_in[3];
  const float* bh0 = (const float*)d_in[4];
  const float* Wi1 = (const float*)d_in[5];
  const float* bi1 = (const float*)d_in[6];
  const float* Wh1 = (const float*)d_in[7];
  const float* bh1 = (const float*)d_in[8];
  const float* Wi2 = (const float*)d_in[9];
  const float* bi2 = (const float*)d_in[10];
  const float* Wh2 = (const float*)d_in[11];
  const float* bh2 = (const float*)d_in[12];
  float* out = (float*)d_out;
  (void)in_sizes; (void)n_in; (void)out_size; (void)ws_size;

  char* ws = (char*)d_ws;
  size_t off = 0;
  auto alloc = [&](size_t b) { char* p = ws + off; off = (off + b + 255) & ~(size_t)255; return p; };
  short* xth   = (short*)alloc(16384ull * 256 * 2);   // 8.4 MB
  short* xtl   = (short*)alloc(16384ull * 256 * 2);
  short* hg    = (short*)alloc(3ull * 6 * HSZ * 2);   // 3 layers x [3buf][hi/lo][32][512]
  int*   flags = (int*)alloc(NBLK * 32 * 4);
  int*   agg   = (int*)alloc(3 * 16 * 4);

  hipMemsetAsync(flags, 0, NBLK * 32 * 4, stream);
  hipMemsetAsync(agg, 0, 3 * 16 * 4, stream);
  hipLaunchKernelGGL(conv_x_k, dim3(4096), dim3(256), 0, stream, x, xth, xtl);
  hipLaunchKernelGGL(rec3, dim3(NBLK + 3), dim3(256), 0, stream,
                     xth, xtl,
                     Wi0, bi0, Wh0, bh0,
                     Wi1, bi1, Wh1, bh1,
                     Wi2, bi2, Wh2, bh2,
                     hg, flags, agg, out);
}